// Round 13
// baseline (453.916 us; speedup 1.0000x reference)
//
#include <hip/hip_runtime.h>

#define B_ 256
#define D_ 128
#define T_ 1024
#define H_ 64
#define G_ 192
#define TILE_T 64
#define NTILES (T_ / TILE_T)   // 16
#define XGS 65                 // ring t-stride: 65%32=1 -> 2-way max (free)
#define KC 32                  // producer k-chunk
#define WS 194                 // w_s g-stride

typedef float f32x4 __attribute__((ext_vector_type(4)));

// Fused GRU, 1 launch. Block = 1 batch row, 5 waves (320 thr), 1 block/CU.
//   wave 0    : scan, ALL THREE gate dots in one wave, f32 weights.
//               Round-13: amdgpu_num_vgpr(256) — a direct arch-VGPR request,
//               not an occupancy hint. Diagnosis: r11's asm kept 192 weights
//               live yet VGPR_Count=124 + clean WRITE_SIZE => the allocator
//               spilled them to AGPRs (gfx950 unified file; invisible in
//               scratch traffic), costing ~2cyc v_accvgpr_read per use
//               (~380 cyc/step) — why removing the hop (r10->r11) was null.
//               2 waves/SIMD x 256 VGPR = 512 = exactly the file => feasible.
//   waves 1..4: register-tiled GEMM producers -> LDS ring (r8 verbatim).
// Sync via LDS atomic flags only; s_barrier once at start.
// (r12's f16-weight scan FAILED precision: absmax 0.159 — systematic W
// quantization compounds over T=1024. Recurrent path must stay f32.)
__global__ __attribute__((amdgpu_num_vgpr(256))) __launch_bounds__(320)
void gru_fused(
    const float* __restrict__ lat, const float* __restrict__ hidden_init,
    const float* __restrict__ W_ih, const float* __restrict__ W_hh,
    const float* __restrict__ b_ih, const float* __restrict__ b_hh,
    const float* __restrict__ head_w, const float* __restrict__ head_b,
    float* __restrict__ out)
{
    __shared__ float xg_s[2][G_ * XGS];     // 99,840 B ring [slot][g*XGS+t]
    __shared__ float lat_s[D_ * TILE_T];    // 32,768 B [d][t]
    __shared__ float w_s[KC * WS];          // 24,832 B [kk][g]
    __shared__ float h_s[H_];
    __shared__ unsigned prod_done[2], cons_done[2], pbar;

    const int b    = blockIdx.x;
    const int tid  = threadIdx.x;
    const int lane = tid & 63;
    const int wid  = tid >> 6;

    if (tid < 2) { prod_done[tid] = 0u; cons_done[tid] = 0u; }
    if (tid == 2) pbar = 0u;
    __syncthreads();   // only workgroup barrier (all 5 waves present)

    if (wid == 0) {
        // ========== scan: single wave, all gates, no inter-wave hops ==========
        __builtin_amdgcn_s_setprio(1);
        const int j = lane;
        f32x4 wr4[16], wz4[16], wn4[16];
        {
            const f32x4* Wr = (const f32x4*)(W_hh + (size_t)j * H_);
            const f32x4* Wz = (const f32x4*)(W_hh + (size_t)(H_ + j) * H_);
            const f32x4* Wn = (const f32x4*)(W_hh + (size_t)(2 * H_ + j) * H_);
#pragma unroll
            for (int q = 0; q < 16; ++q) { wr4[q] = Wr[q]; wz4[q] = Wz[q]; wn4[q] = Wn[q]; }
        }
        // prevent rematerialization of the 48 weight quads
        asm volatile("" : "+v"(wr4[0]), "+v"(wr4[1]), "+v"(wr4[2]), "+v"(wr4[3]),
                          "+v"(wr4[4]), "+v"(wr4[5]), "+v"(wr4[6]), "+v"(wr4[7]),
                          "+v"(wr4[8]), "+v"(wr4[9]), "+v"(wr4[10]), "+v"(wr4[11]),
                          "+v"(wr4[12]), "+v"(wr4[13]), "+v"(wr4[14]), "+v"(wr4[15]));
        asm volatile("" : "+v"(wz4[0]), "+v"(wz4[1]), "+v"(wz4[2]), "+v"(wz4[3]),
                          "+v"(wz4[4]), "+v"(wz4[5]), "+v"(wz4[6]), "+v"(wz4[7]),
                          "+v"(wz4[8]), "+v"(wz4[9]), "+v"(wz4[10]), "+v"(wz4[11]),
                          "+v"(wz4[12]), "+v"(wz4[13]), "+v"(wz4[14]), "+v"(wz4[15]));
        asm volatile("" : "+v"(wn4[0]), "+v"(wn4[1]), "+v"(wn4[2]), "+v"(wn4[3]),
                          "+v"(wn4[4]), "+v"(wn4[5]), "+v"(wn4[6]), "+v"(wn4[7]),
                          "+v"(wn4[8]), "+v"(wn4[9]), "+v"(wn4[10]), "+v"(wn4[11]),
                          "+v"(wn4[12]), "+v"(wn4[13]), "+v"(wn4[14]), "+v"(wn4[15]));
        const float br = b_hh[j], bz = b_hh[H_ + j], bn = b_hh[2 * H_ + j];
        const float hw = head_w[j];
        float h = hidden_init[b * H_ + j];

        for (int k = 0; k < NTILES; ++k) {
            const int s = k & 1;
            const unsigned tgt = 4u * (unsigned)((k >> 1) + 1);   // 4 producers
            while (__hip_atomic_load(&prod_done[s], __ATOMIC_ACQUIRE,
                                     __HIP_MEMORY_SCOPE_WORKGROUP) < tgt)
                __builtin_amdgcn_s_sleep(1);
            const float* xr_p = &xg_s[s][(size_t)j * XGS];
            const float* xz_p = &xg_s[s][(size_t)(H_ + j) * XGS];
            const float* xn_p = &xg_s[s][(size_t)(2 * H_ + j) * XGS];

#pragma unroll 2
            for (int t = 0; t < TILE_T; ++t) {
                h_s[j] = h;                       // within-wave: DS in-order
                float xr = xr_p[t], xz = xz_p[t], xn = xn_p[t];
                const f32x4* h4 = (const f32x4*)h_s;
                f32x4 aR = {0.f, 0.f, 0.f, 0.f};
                f32x4 aZ = {0.f, 0.f, 0.f, 0.f};
                f32x4 aN = {0.f, 0.f, 0.f, 0.f};
#pragma unroll
                for (int q = 0; q < 16; ++q) {
                    f32x4 hv = h4[q];             // broadcast read, shared by 3 gates
                    aR += wr4[q] * hv;            // v_pk_fma_f32
                    aZ += wz4[q] * hv;
                    aN += wn4[q] * hv;
                }
                float ar = ((aR.x + aR.y) + (aR.z + aR.w)) + br;
                float az = ((aZ.x + aZ.y) + (aZ.z + aZ.w)) + bz;
                float an = ((aN.x + aN.y) + (aN.z + aN.w)) + bn;

                float r   = __builtin_amdgcn_rcpf(1.f + __expf(-(xr + ar)));
                float z   = __builtin_amdgcn_rcpf(1.f + __expf(-(xz + az)));
                float pre = xn + r * an;
                float n   = fmaf(-2.f, __builtin_amdgcn_rcpf(__expf(2.f * pre) + 1.f), 1.f);
                h = fmaf(z, h - n, n);            // (1-z)n + zh
            }
            if (lane == 0)
                __hip_atomic_fetch_add(&cons_done[s], 1u, __ATOMIC_RELEASE,
                                       __HIP_MEMORY_SCOPE_WORKGROUP);
        }

        // epilogue: final hidden + head
        out[B_ + b * H_ + j] = h;
        float v = h * hw;
#pragma unroll
        for (int off = 32; off > 0; off >>= 1) v += __shfl_down(v, off);
        if (lane == 0) out[b] = v + head_b[0];
    } else {
        // ============ producers: register-tiled GEMM (r8 verbatim) ============
        const int p  = tid - 64;         // 0..255
        const int tx = p & 7;            // t-sub: t = tx*8 + jj
        const int gy = p >> 3;           // g-sub: g = gy*6 + i
        const float* latb = lat + (size_t)b * (D_ * T_);
        unsigned phase = 0;

        auto psync = [&]() {
            if ((p & 63) == 0)
                __hip_atomic_fetch_add(&pbar, 1u, __ATOMIC_RELEASE,
                                       __HIP_MEMORY_SCOPE_WORKGROUP);
            ++phase;
            while (__hip_atomic_load(&pbar, __ATOMIC_ACQUIRE,
                                     __HIP_MEMORY_SCOPE_WORKGROUP) < 4u * phase) {}
        };

        float bias[6];
#pragma unroll
        for (int i = 0; i < 6; ++i) bias[i] = b_ih[gy * 6 + i];

        for (int k = 0; k < NTILES; ++k) {
            const int s = k & 1, m = k >> 1;
            if (m >= 1) {
                while (__hip_atomic_load(&cons_done[s], __ATOMIC_ACQUIRE,
                                         __HIP_MEMORY_SCOPE_WORKGROUP) < (unsigned)m)
                    __builtin_amdgcn_s_sleep(1);
            }
            psync();   // all producers past previous tile's lat_s/w_s

            // stage lat tile [d][t] (coalesced)
#pragma unroll
            for (int i = 0; i < 32; ++i) {
                int f = p + 256 * i;           // f = d*64 + t
                int d = f >> 6, t = f & 63;
                lat_s[f] = latb[(size_t)d * T_ + k * TILE_T + t];
            }

            float acc[8][6];
#pragma unroll
            for (int jj = 0; jj < 8; ++jj)
#pragma unroll
                for (int i = 0; i < 6; ++i) acc[jj][i] = 0.f;

            for (int kc = 0; kc < D_; kc += KC) {
                psync();   // lat_s staged / previous w_s consumed
#pragma unroll
                for (int i = 0; i < (G_ * KC) / 256; ++i) {   // 24/thread
                    int f = p + 256 * i;
                    int g = f >> 5, kk = f & 31;
                    w_s[kk * WS + g] = W_ih[(size_t)g * D_ + kc + kk];
                }
                psync();   // w_s ready
#pragma unroll 4
                for (int kk = 0; kk < KC; ++kk) {
                    f32x4 l0 = *(const f32x4*)&lat_s[(kc + kk) * 64 + tx * 8];
                    f32x4 l1 = *(const f32x4*)&lat_s[(kc + kk) * 64 + tx * 8 + 4];
                    float2 w0 = *(const float2*)&w_s[kk * WS + gy * 6];
                    float2 w1 = *(const float2*)&w_s[kk * WS + gy * 6 + 2];
                    float2 w2 = *(const float2*)&w_s[kk * WS + gy * 6 + 4];
                    float lv[8] = {l0.x, l0.y, l0.z, l0.w, l1.x, l1.y, l1.z, l1.w};
                    float wv[6] = {w0.x, w0.y, w1.x, w1.y, w2.x, w2.y};
#pragma unroll
                    for (int jj = 0; jj < 8; ++jj)
#pragma unroll
                        for (int i = 0; i < 6; ++i)
                            acc[jj][i] = fmaf(lv[jj], wv[i], acc[jj][i]);
                }
            }

            // write tile to ring slot
            float* xs = xg_s[s];
#pragma unroll
            for (int i = 0; i < 6; ++i)
#pragma unroll
                for (int jj = 0; jj < 8; ++jj)
                    xs[(size_t)(gy * 6 + i) * XGS + tx * 8 + jj] = acc[jj][i] + bias[i];

            if ((p & 63) == 0)
                __hip_atomic_fetch_add(&prod_done[s], 1u, __ATOMIC_RELEASE,
                                       __HIP_MEMORY_SCOPE_WORKGROUP);
        }
    }
}

extern "C" void kernel_launch(void* const* d_in, const int* in_sizes, int n_in,
                              void* d_out, int out_size, void* d_ws, size_t ws_size,
                              hipStream_t stream)
{
    const float* lat   = (const float*)d_in[0];
    const float* hid0  = (const float*)d_in[1];
    const float* W_ih  = (const float*)d_in[2];
    const float* W_hh  = (const float*)d_in[3];
    const float* b_ih  = (const float*)d_in[4];
    const float* b_hh  = (const float*)d_in[5];
    const float* headw = (const float*)d_in[6];
    const float* headb = (const float*)d_in[7];
    float* out = (float*)d_out;

    gru_fused<<<dim3(B_), dim3(320), 0, stream>>>(
        lat, hid0, W_ih, W_hh, b_ih, b_hh, headw, headb, out);
}